// Round 1
// baseline (286.837 us; speedup 1.0000x reference)
//
#include <hip/hip_runtime.h>
#include <hip/hip_fp16.h>

#define N_    8
#define CIN   128
#define COUT  128
#define H_    128
#define W_    128
#define HO    126
#define WO    126
#define PIXPER (HO*WO)            // 15876
#define TOTPIX (N_*PIXPER)        // 127008
#define PT    128                 // pixels per block
#define BLKPERIMG 125             // ceil(15876/128): last block has 4 valid px
#define NBLK  (N_*BLKPERIMG)      // 1000; bid&7 = image

typedef _Float16 f16x8 __attribute__((ext_vector_type(8)));
typedef _Float16 f16x4 __attribute__((ext_vector_type(4)));
typedef float    f32x4 __attribute__((ext_vector_type(4)));

union U4H {
    uint4   u;
    __half2 h[4];
    f16x8   f;
};

// ---------------------------------------------------------------------------
// Kernel: input [N][C][H*W] fp32 -> channels-last fp16 [N][H*W][C]
// (unchanged — known-good; need per-dispatch timing before touching it)
// ---------------------------------------------------------------------------
__global__ __launch_bounds__(256) void transpose_in_kernel(
    const float* __restrict__ in, _Float16* __restrict__ in_cl)
{
    __shared__ float tile[64][65];
    int bid = blockIdx.x;
    int hwt = bid & 255;          // HW/64 = 256
    int ct  = (bid >> 8) & 1;     // C/64 = 2
    int n   = bid >> 9;           // N = 8
    int r0  = threadIdx.x >> 4;   // 0..15
    int c4  = (threadIdx.x & 15) * 4;
    const float* src = in + ((size_t)(n * CIN + ct * 64) * 16384) + hwt * 64;
#pragma unroll
    for (int k = 0; k < 4; ++k) {
        int row = r0 + k * 16;                      // c within tile
        float4 v = *(const float4*)(src + (size_t)row * 16384 + c4);
        *(float4*)&tile[row][c4] = v;               // [c][hw]
    }
    __syncthreads();
    _Float16* dst = in_cl + ((size_t)(n * 16384 + hwt * 64) * 128) + ct * 64;
#pragma unroll
    for (int k = 0; k < 4; ++k) {
        int hw = r0 + k * 16;
        f16x4 o;
        o[0] = (_Float16)tile[c4 + 0][hw];
        o[1] = (_Float16)tile[c4 + 1][hw];
        o[2] = (_Float16)tile[c4 + 2][hw];
        o[3] = (_Float16)tile[c4 + 3][hw];
        *(f16x4*)(dst + (size_t)hw * 128 + c4) = o;
    }
}

// ---------------------------------------------------------------------------
// Kernel: weight [O][C][3][3] fp32 -> wt [tap][O][C] fp16 (c contiguous)
// ---------------------------------------------------------------------------
__global__ void transpose_w_kernel(const float* __restrict__ w, _Float16* __restrict__ wt) {
    int t = blockIdx.x * 256 + threadIdx.x;   // 16384 threads
    int o = t >> 7, c = t & 127;
    const float* s = w + (size_t)(o * 128 + c) * 9;
#pragma unroll
    for (int tap = 0; tap < 9; ++tap)
        wt[tap * 16384 + o * 128 + c] = (_Float16)s[tap];
}

// ---------------------------------------------------------------------------
// Main kernel v2. Block = 128 px x 128 o, 4 waves.
// B-frags are built DIRECTLY in registers from channels-last global memory:
// lane (quad,l15) loads its own 16B channel slice of its own pixel's corner
// rows (4 quads of a fixed l15 cover one full 64B line -> line-perfect
// coalescing, same total L2 bytes as the old sS-staged scheme).
// This deletes sS (34.8 KB) + param LDS (6 KB): LDS = sW only (32 KB)
// -> 4 blocks/CU at VGPR<=128 (was 2 blocks/CU), and kills the sS bank
// conflicts. Per-pixel params (rate, ho/wo) live in registers per lane.
// Per tap: {build bf in regs} barrier {stage sW} barrier {64 MFMA}.
// ---------------------------------------------------------------------------
__global__ __launch_bounds__(256, 4) void adc_main(
    const _Float16* __restrict__ in_cl, const _Float16* __restrict__ wt,
    const float* __restrict__ rates, const float* __restrict__ bias,
    float* __restrict__ out)
{
    __shared__ uint4 sW[2048];                       // 32768 B — only LDS

    const int t    = threadIdx.x;
    const int lane = t & 63;
    const int wv   = t >> 6;
    const int l15  = lane & 15;
    const int quad = lane >> 4;

    const int n     = blockIdx.x & 7;
    const int pbase = (blockIdx.x >> 3) * PT;
    const unsigned nbase = (unsigned)n << 14;

    // ---- per-lane pixel params (2 px per lane; quad-redundant but cheap) ----
    int   hoA[2], woA[2];
    float rA[2];
#pragma unroll
    for (int h = 0; h < 2; ++h) {
        int pc = min(pbase + (wv << 5) + (h << 4) + l15, PIXPER - 1);
        int ho = pc / WO, wo = pc - ho * WO;
        hoA[h] = ho; woA[h] = wo;
        const float sc = 32.0f / 126.0f;
        float sy = fminf(fmaxf(((float)ho + 0.5f) * sc - 0.5f, 0.0f), 31.0f);
        float sx = fminf(fmaxf(((float)wo + 0.5f) * sc - 0.5f, 0.0f), 31.0f);
        int y0 = (int)sy, x0 = (int)sx;
        int y1 = min(y0 + 1, 31), x1 = min(x0 + 1, 31);
        float wy = sy - (float)y0, wx = sx - (float)x0;
        rA[h] = rates[y0 * 32 + x0] * (1.0f - wy) * (1.0f - wx)
              + rates[y0 * 32 + x1] * (1.0f - wy) * wx
              + rates[y1 * 32 + x0] * wy * (1.0f - wx)
              + rates[y1 * 32 + x1] * wy * wx;
    }

    f32x4 acc[8][2];
    const f32x4 zero = {0.0f, 0.0f, 0.0f, 0.0f};
#pragma unroll
    for (int i = 0; i < 8; ++i) { acc[i][0] = zero; acc[i][1] = zero; }

    const unsigned co = (unsigned)(quad << 3);       // half-offset in 128-ch row

#pragma unroll
    for (int tap = 0; tap < 9; ++tap) {
        const int kh = tap / 3;            // compile-time after unroll
        const int kw = tap - kh * 3;

        // ---- build B-frags in registers (no LDS touched) ----
        f16x8 bf[2][4];
#pragma unroll
        for (int h = 0; h < 2; ++h) {
            const int   ho = hoA[h], wo = woA[h];
            const float r  = rA[h];
            int y0, x0; float wy, wx;
            if (kh == 0) { y0 = ho; wy = 0.0f; }
            else {
                float fy = (float)ho + (float)kh * r;
                float f0 = floorf(fy); y0 = (int)f0; wy = fy - f0;
            }
            if (kw == 0) { x0 = wo; wx = 0.0f; }
            else {
                float fx = (float)wo + (float)kw * r;
                float f0 = floorf(fx); x0 = (int)f0; wx = fx - f0;
            }
            const int yc0 = min(y0, H_ - 1), yc1 = min(y0 + 1, H_ - 1);
            const int xc0 = min(x0, W_ - 1), xc1 = min(x0 + 1, W_ - 1);
            const unsigned a00 = ((nbase + (unsigned)(yc0 * W_ + xc0)) << 7) + co;
            const unsigned a01 = ((nbase + (unsigned)(yc0 * W_ + xc1)) << 7) + co;
            const unsigned a10 = ((nbase + (unsigned)(yc1 * W_ + xc0)) << 7) + co;
            const unsigned a11 = ((nbase + (unsigned)(yc1 * W_ + xc1)) << 7) + co;

            if (kh == 0 && kw == 0) {
                // wy=wx=0 exactly: passthrough
#pragma unroll
                for (int ks = 0; ks < 4; ++ks) {
                    U4H A; A.u = *(const uint4*)(in_cl + a00 + ks * 32);
                    bf[h][ks] = A.f;
                }
            } else {
                const float vy0 = (y0 <= H_ - 1) ? 1.0f : 0.0f;
                const float vy1 = (y0 <= H_ - 2) ? 1.0f : 0.0f;
                const float vx0 = (x0 <= W_ - 1) ? 1.0f : 0.0f;
                const float vx1 = (x0 <= W_ - 2) ? 1.0f : 0.0f;
                const __half2 w00v = __float2half2_rn((1.0f - wy) * (1.0f - wx) * vy0 * vx0);
                const __half2 w01v = __float2half2_rn((1.0f - wy) * wx * vy0 * vx1);
                const __half2 w10v = __float2half2_rn(wy * (1.0f - wx) * vy1 * vx0);
                const __half2 w11v = __float2half2_rn(wy * wx * vy1 * vx1);
#pragma unroll
                for (int ks = 0; ks < 4; ++ks) {
                    U4H A, B, C, D, S;
                    A.u = *(const uint4*)(in_cl + a00 + ks * 32);
                    if (kw != 0) B.u = *(const uint4*)(in_cl + a01 + ks * 32);
                    if (kh != 0) C.u = *(const uint4*)(in_cl + a10 + ks * 32);
                    if (kh != 0 && kw != 0)
                                 D.u = *(const uint4*)(in_cl + a11 + ks * 32);
#pragma unroll
                    for (int d = 0; d < 4; ++d) {
                        __half2 s = __hmul2(A.h[d], w00v);
                        if (kw != 0)            s = __hfma2(B.h[d], w01v, s);
                        if (kh != 0)            s = __hfma2(C.h[d], w10v, s);
                        if (kh != 0 && kw != 0) s = __hfma2(D.h[d], w11v, s);
                        S.h[d] = s;
                    }
                    bf[h][ks] = S.f;
                }
            }
        }

        // ---- stage W[tap] into sW (swizzled, as before) ----
        __syncthreads();                   // prev tap's MFMA reads done
        const uint4* wsrc = (const uint4*)(wt + tap * 16384);
#pragma unroll
        for (int i = 0; i < 8; ++i) {
            int gi = i * 256 + t;
            int o = gi >> 4, g = gi & 15;
            sW[(o << 4) | (g ^ (o & 7))] = wsrc[gi];
        }
        __syncthreads();

        // ---- MFMA: A from sW, B from registers ----
#pragma unroll
        for (int ks = 0; ks < 4; ++ks) {
#pragma unroll
            for (int mt = 0; mt < 8; ++mt) {
                int o = (mt << 4) | l15;
                int g = (ks << 2) | quad;
                U4H AF;
                AF.u = sW[(o << 4) | (g ^ (o & 7))];
                acc[mt][0] = __builtin_amdgcn_mfma_f32_16x16x32_f16(AF.f, bf[0][ks], acc[mt][0], 0, 0, 0);
                acc[mt][1] = __builtin_amdgcn_mfma_f32_16x16x32_f16(AF.f, bf[1][ks], acc[mt][1], 0, 0, 0);
            }
        }
    }

    // ---- epilogue: R3-proven direct strided stores (unchanged) ----
#pragma unroll
    for (int pt = 0; pt < 2; ++pt) {
        int p    = (wv << 5) + (pt << 4) + l15;
        int prel = pbase + p;
        int rem2 = min(prel, PIXPER - 1);
        float* obase = out + (size_t)n * (COUT * PIXPER) + rem2;
        if (prel < PIXPER) {
#pragma unroll
            for (int mt = 0; mt < 8; ++mt) {
                int o0 = (mt << 4) + (quad << 2);
                float4 bs = *(const float4*)(bias + o0);
                f32x4 a0 = acc[mt][pt];
                obase[(size_t)(o0 + 0) * PIXPER] = a0[0] + bs.x;
                obase[(size_t)(o0 + 1) * PIXPER] = a0[1] + bs.y;
                obase[(size_t)(o0 + 2) * PIXPER] = a0[2] + bs.z;
                obase[(size_t)(o0 + 3) * PIXPER] = a0[3] + bs.w;
            }
        }
    }
}

// ---------------------------------------------------------------------------
extern "C" void kernel_launch(void* const* d_in, const int* in_sizes, int n_in,
                              void* d_out, int out_size, void* d_ws, size_t ws_size,
                              hipStream_t stream) {
    const float* inputs = (const float*)d_in[0];   // [8,128,128,128]
    const float* weight = (const float*)d_in[1];   // [128,128,3,3]
    const float* rates  = (const float*)d_in[2];   // [1,1,32,32]
    const float* bias   = (const float*)d_in[3];   // [128]
    float* out = (float*)d_out;                    // [8,128,126,126]

    char* ws = (char*)d_ws;
    _Float16* in_cl = (_Float16*)ws;                         // 33,554,432 B
    _Float16* wtp   = (_Float16*)(ws + 33554432);            //    294,912 B

    transpose_w_kernel<<<64, 256, 0, stream>>>(weight, wtp);
    transpose_in_kernel<<<4096, 256, 0, stream>>>(inputs, in_cl);
    adc_main<<<NBLK, 256, 0, stream>>>(in_cl, wtp, rates, bias, out);
}

// Round 3
// 241.778 us; speedup vs baseline: 1.1864x; 1.1864x over previous
//
#include <hip/hip_runtime.h>
#include <hip/hip_fp16.h>

#define N_    8
#define CIN   128
#define COUT  128
#define H_    128
#define W_    128
#define HO    126
#define WO    126
#define PIXPER (HO*WO)            // 15876
#define TOTPIX (N_*PIXPER)        // 127008
#define PT    128                 // pixels per block
#define BLKPERIMG 125             // ceil(15876/128): last block has 4 valid px
#define NBLK  (N_*BLKPERIMG)      // 1000; bid&7 = image

typedef _Float16 f16x8 __attribute__((ext_vector_type(8)));
typedef _Float16 f16x4 __attribute__((ext_vector_type(4)));
typedef float    f32x4 __attribute__((ext_vector_type(4)));

union U4H {
    uint4   u;
    __half2 h[4];
    f16x8   f;
};

// global->LDS async, 16B per lane; LDS dest = wave-uniform base + lane*16
#define GLLDS(gp, lp) __builtin_amdgcn_global_load_lds( \
    (const __attribute__((address_space(1))) unsigned int*)(gp), \
    (__attribute__((address_space(3))) unsigned int*)(lp), 16, 0, 0)

// ---------------------------------------------------------------------------
// Kernel: input [N][C][H*W] fp32 -> channels-last fp16 [N][H*W][C]
// (unchanged — known-good)
// ---------------------------------------------------------------------------
__global__ __launch_bounds__(256) void transpose_in_kernel(
    const float* __restrict__ in, _Float16* __restrict__ in_cl)
{
    __shared__ float tile[64][65];
    int bid = blockIdx.x;
    int hwt = bid & 255;          // HW/64 = 256
    int ct  = (bid >> 8) & 1;     // C/64 = 2
    int n   = bid >> 9;           // N = 8
    int r0  = threadIdx.x >> 4;   // 0..15
    int c4  = (threadIdx.x & 15) * 4;
    const float* src = in + ((size_t)(n * CIN + ct * 64) * 16384) + hwt * 64;
#pragma unroll
    for (int k = 0; k < 4; ++k) {
        int row = r0 + k * 16;                      // c within tile
        float4 v = *(const float4*)(src + (size_t)row * 16384 + c4);
        *(float4*)&tile[row][c4] = v;               // [c][hw]
    }
    __syncthreads();
    _Float16* dst = in_cl + ((size_t)(n * 16384 + hwt * 64) * 128) + ct * 64;
#pragma unroll
    for (int k = 0; k < 4; ++k) {
        int hw = r0 + k * 16;
        f16x4 o;
        o[0] = (_Float16)tile[c4 + 0][hw];
        o[1] = (_Float16)tile[c4 + 1][hw];
        o[2] = (_Float16)tile[c4 + 2][hw];
        o[3] = (_Float16)tile[c4 + 3][hw];
        *(f16x4*)(dst + (size_t)hw * 128 + c4) = o;
    }
}

// ---------------------------------------------------------------------------
// Kernel: weight [O][C][3][3] fp32 -> wt [tap][swizzled O*C] fp16.
// PRE-SWIZZLED so adc_main's staging is a linear copy (global_load_lds-able)
// and the MFMA-phase read keeps the conflict-spread XOR pattern.
// Element (o, c) lands at uint4-index (o<<4)|((c>>3)^(o&7)), half (c&7).
// ---------------------------------------------------------------------------
__global__ void transpose_w_kernel(const float* __restrict__ w, _Float16* __restrict__ wt) {
    int t = blockIdx.x * 256 + threadIdx.x;   // 16384 threads
    int o = t >> 7, c = t & 127;
    int g = c >> 3;
    int dst = (((o << 4) | (g ^ (o & 7))) << 3) | (c & 7);
    const float* s = w + (size_t)(o * 128 + c) * 9;
#pragma unroll
    for (int tap = 0; tap < 9; ++tap)
        wt[tap * 16384 + dst] = (_Float16)s[tap];
}

// ---------------------------------------------------------------------------
// Main kernel v3. Block = 128 px x 128 o, 4 waves.
// v2 failed on register spills (launch_bounds(256,4) -> 64 arch VGPRs vs
// bf[2][4]+gather temps; 197MB scratch writes). v3 keeps the register-direct
// B-frag gather but moves it INSIDE the ks loop so only one ks-slice of
// gather temps is live at a time:
//   per tap: {addr+lerp-weight precompute (16 regs)} -> barrier ->
//            {async global_load_lds sW stage, overlapped with nothing to do}
//            -> barrier -> for ks: {gather 2-8 x 16B, lerp -> bf[2]} ; 16 MFMA
// Peak live ~ 64 acc + 16 addr/wt + ~32 transient => fits 3 waves/EU (~170
// regs) with zero scratch. LDS = sW only (32KB); occupancy 12 waves/CU.
// ---------------------------------------------------------------------------
__global__ __launch_bounds__(256, 3) void adc_main(
    const _Float16* __restrict__ in_cl, const _Float16* __restrict__ wt,
    const float* __restrict__ rates, const float* __restrict__ bias,
    float* __restrict__ out)
{
    __shared__ uint4 sW[2048];                       // 32768 B — only LDS

    const int t    = threadIdx.x;
    const int lane = t & 63;
    const int wv   = t >> 6;
    const int l15  = lane & 15;
    const int quad = lane >> 4;

    const int n     = blockIdx.x & 7;
    const int pbase = (blockIdx.x >> 3) * PT;
    const unsigned nbase = (unsigned)n << 14;

    // ---- per-lane pixel params (2 px per lane; quad-redundant but cheap) ----
    int   hoA[2], woA[2];
    float rA[2];
#pragma unroll
    for (int h = 0; h < 2; ++h) {
        int pc = min(pbase + (wv << 5) + (h << 4) + l15, PIXPER - 1);
        int ho = pc / WO, wo = pc - ho * WO;
        hoA[h] = ho; woA[h] = wo;
        const float sc = 32.0f / 126.0f;
        float sy = fminf(fmaxf(((float)ho + 0.5f) * sc - 0.5f, 0.0f), 31.0f);
        float sx = fminf(fmaxf(((float)wo + 0.5f) * sc - 0.5f, 0.0f), 31.0f);
        int y0 = (int)sy, x0 = (int)sx;
        int y1 = min(y0 + 1, 31), x1 = min(x0 + 1, 31);
        float wy = sy - (float)y0, wx = sx - (float)x0;
        rA[h] = rates[y0 * 32 + x0] * (1.0f - wy) * (1.0f - wx)
              + rates[y0 * 32 + x1] * (1.0f - wy) * wx
              + rates[y1 * 32 + x0] * wy * (1.0f - wx)
              + rates[y1 * 32 + x1] * wy * wx;
    }

    f32x4 acc[8][2];
    const f32x4 zero = {0.0f, 0.0f, 0.0f, 0.0f};
#pragma unroll
    for (int i = 0; i < 8; ++i) { acc[i][0] = zero; acc[i][1] = zero; }

    const unsigned co = (unsigned)(quad << 3);       // 16B chunk within 128-ch row

#pragma unroll
    for (int tap = 0; tap < 9; ++tap) {
        const int kh = tap / 3;            // compile-time after unroll
        const int kw = tap - kh * 3;

        // ---- per-tap corner addresses + lerp weights (registers, 16 live) ----
        unsigned a00[2], a01[2], a10[2], a11[2];
        __half2  w00v[2], w01v[2], w10v[2], w11v[2];
#pragma unroll
        for (int h = 0; h < 2; ++h) {
            const int   ho = hoA[h], wo = woA[h];
            const float r  = rA[h];
            int y0, x0; float wy, wx;
            if (kh == 0) { y0 = ho; wy = 0.0f; }
            else {
                float fy = (float)ho + (float)kh * r;
                float f0 = floorf(fy); y0 = (int)f0; wy = fy - f0;
            }
            if (kw == 0) { x0 = wo; wx = 0.0f; }
            else {
                float fx = (float)wo + (float)kw * r;
                float f0 = floorf(fx); x0 = (int)f0; wx = fx - f0;
            }
            const int yc0 = min(y0, H_ - 1), yc1 = min(y0 + 1, H_ - 1);
            const int xc0 = min(x0, W_ - 1), xc1 = min(x0 + 1, W_ - 1);
            a00[h] = ((nbase + (unsigned)(yc0 * W_ + xc0)) << 7) + co;
            a01[h] = ((nbase + (unsigned)(yc0 * W_ + xc1)) << 7) + co;
            a10[h] = ((nbase + (unsigned)(yc1 * W_ + xc0)) << 7) + co;
            a11[h] = ((nbase + (unsigned)(yc1 * W_ + xc1)) << 7) + co;
            if (!(kh == 0 && kw == 0)) {
                const float vy0 = (y0 <= H_ - 1) ? 1.0f : 0.0f;
                const float vy1 = (y0 <= H_ - 2) ? 1.0f : 0.0f;
                const float vx0 = (x0 <= W_ - 1) ? 1.0f : 0.0f;
                const float vx1 = (x0 <= W_ - 2) ? 1.0f : 0.0f;
                w00v[h] = __float2half2_rn((1.0f - wy) * (1.0f - wx) * vy0 * vx0);
                w01v[h] = __float2half2_rn((1.0f - wy) * wx * vy0 * vx1);
                w10v[h] = __float2half2_rn(wy * (1.0f - wx) * vy1 * vx0);
                w11v[h] = __float2half2_rn(wy * wx * vy1 * vx1);
            }
        }

        // ---- stage W[tap]: linear async copy (wt pre-swizzled on host side) ----
        __syncthreads();                   // prev tap's MFMA reads done
        const uint4* wsrc = (const uint4*)(wt + tap * 16384);
#pragma unroll
        for (int i = 0; i < 8; ++i) {
            int base = i * 256 + (wv << 6);
            GLLDS(wsrc + base + lane, &sW[base]);
        }
        __syncthreads();                   // drains vmcnt -> sW ready

        // ---- per-ks: gather+lerp bf in regs, then 16 MFMA ----
#pragma unroll
        for (int ks = 0; ks < 4; ++ks) {
            f16x8 bfr[2];
#pragma unroll
            for (int h = 0; h < 2; ++h) {
                U4H A, B, C, D;
                A.u = *(const uint4*)(in_cl + a00[h] + ks * 32);
                if (kw != 0) B.u = *(const uint4*)(in_cl + a01[h] + ks * 32);
                if (kh != 0) C.u = *(const uint4*)(in_cl + a10[h] + ks * 32);
                if (kh != 0 && kw != 0)
                             D.u = *(const uint4*)(in_cl + a11[h] + ks * 32);
                if (kh == 0 && kw == 0) {
                    bfr[h] = A.f;          // wy=wx=0 exactly: passthrough
                } else {
                    U4H S;
#pragma unroll
                    for (int d = 0; d < 4; ++d) {
                        __half2 s = __hmul2(A.h[d], w00v[h]);
                        if (kw != 0)            s = __hfma2(B.h[d], w01v[h], s);
                        if (kh != 0)            s = __hfma2(C.h[d], w10v[h], s);
                        if (kh != 0 && kw != 0) s = __hfma2(D.h[d], w11v[h], s);
                        S.h[d] = s;
                    }
                    bfr[h] = S.f;
                }
            }
#pragma unroll
            for (int mt = 0; mt < 8; ++mt) {
                const int o = (mt << 4) | l15;
                const int g = (ks << 2) | quad;
                U4H AF;
                AF.u = sW[(o << 4) | (g ^ (l15 & 7))];   // o&7 == l15&7
                acc[mt][0] = __builtin_amdgcn_mfma_f32_16x16x32_f16(AF.f, bfr[0], acc[mt][0], 0, 0, 0);
                acc[mt][1] = __builtin_amdgcn_mfma_f32_16x16x32_f16(AF.f, bfr[1], acc[mt][1], 0, 0, 0);
            }
        }
    }

    // ---- epilogue: R3-proven direct strided stores (unchanged) ----
#pragma unroll
    for (int pt = 0; pt < 2; ++pt) {
        int p    = (wv << 5) + (pt << 4) + l15;
        int prel = pbase + p;
        int rem2 = min(prel, PIXPER - 1);
        float* obase = out + (size_t)n * (COUT * PIXPER) + rem2;
        if (prel < PIXPER) {
#pragma unroll
            for (int mt = 0; mt < 8; ++mt) {
                int o0 = (mt << 4) + (quad << 2);
                float4 bs = *(const float4*)(bias + o0);
                f32x4 a0 = acc[mt][pt];
                obase[(size_t)(o0 + 0) * PIXPER] = a0[0] + bs.x;
                obase[(size_t)(o0 + 1) * PIXPER] = a0[1] + bs.y;
                obase[(size_t)(o0 + 2) * PIXPER] = a0[2] + bs.z;
                obase[(size_t)(o0 + 3) * PIXPER] = a0[3] + bs.w;
            }
        }
    }
}

// ---------------------------------------------------------------------------
extern "C" void kernel_launch(void* const* d_in, const int* in_sizes, int n_in,
                              void* d_out, int out_size, void* d_ws, size_t ws_size,
                              hipStream_t stream) {
    const float* inputs = (const float*)d_in[0];   // [8,128,128,128]
    const float* weight = (const float*)d_in[1];   // [128,128,3,3]
    const float* rates  = (const float*)d_in[2];   // [1,1,32,32]
    const float* bias   = (const float*)d_in[3];   // [128]
    float* out = (float*)d_out;                    // [8,128,126,126]

    char* ws = (char*)d_ws;
    _Float16* in_cl = (_Float16*)ws;                         // 33,554,432 B
    _Float16* wtp   = (_Float16*)(ws + 33554432);            //    294,912 B

    transpose_w_kernel<<<64, 256, 0, stream>>>(weight, wtp);
    transpose_in_kernel<<<4096, 256, 0, stream>>>(inputs, in_cl);
    adc_main<<<NBLK, 256, 0, stream>>>(in_cl, wtp, rates, bias, out);
}

// Round 4
// 186.327 us; speedup vs baseline: 1.5394x; 1.2976x over previous
//
#include <hip/hip_runtime.h>
#include <hip/hip_fp16.h>

#define N_    8
#define CIN   128
#define COUT  128
#define H_    128
#define W_    128
#define HO    126
#define WO    126
#define PIXPER (HO*WO)            // 15876
#define TOTPIX (N_*PIXPER)        // 127008
#define PT    128                 // pixels per block
#define BLKPERIMG 125             // ceil(15876/128): last block has 4 valid px
#define NBLK  (N_*BLKPERIMG)      // 1000; bid&7 = image -> XCD-local L2 reuse

typedef _Float16 f16x8 __attribute__((ext_vector_type(8)));
typedef _Float16 f16x4 __attribute__((ext_vector_type(4)));
typedef float    f32x4 __attribute__((ext_vector_type(4)));

union U4H {
    uint4   u;
    __half2 h[4];
    f16x8   f;
};

// global->LDS async, 16B per lane; LDS dest = wave-uniform base + lane*16
#define GLLDS(gp, lp) __builtin_amdgcn_global_load_lds( \
    (const __attribute__((address_space(1))) unsigned int*)(gp), \
    (__attribute__((address_space(3))) unsigned int*)(lp), 16, 0, 0)

// ---------------------------------------------------------------------------
// Kernel: input [N][C][H*W] fp32 -> channels-last fp16 [N][H*W][C]
// (unchanged — known-good)
// ---------------------------------------------------------------------------
__global__ __launch_bounds__(256) void transpose_in_kernel(
    const float* __restrict__ in, _Float16* __restrict__ in_cl)
{
    __shared__ float tile[64][65];
    int bid = blockIdx.x;
    int hwt = bid & 255;          // HW/64 = 256
    int ct  = (bid >> 8) & 1;     // C/64 = 2
    int n   = bid >> 9;           // N = 8
    int r0  = threadIdx.x >> 4;   // 0..15
    int c4  = (threadIdx.x & 15) * 4;
    const float* src = in + ((size_t)(n * CIN + ct * 64) * 16384) + hwt * 64;
#pragma unroll
    for (int k = 0; k < 4; ++k) {
        int row = r0 + k * 16;                      // c within tile
        float4 v = *(const float4*)(src + (size_t)row * 16384 + c4);
        *(float4*)&tile[row][c4] = v;               // [c][hw]
    }
    __syncthreads();
    _Float16* dst = in_cl + ((size_t)(n * 16384 + hwt * 64) * 128) + ct * 64;
#pragma unroll
    for (int k = 0; k < 4; ++k) {
        int hw = r0 + k * 16;
        f16x4 o;
        o[0] = (_Float16)tile[c4 + 0][hw];
        o[1] = (_Float16)tile[c4 + 1][hw];
        o[2] = (_Float16)tile[c4 + 2][hw];
        o[3] = (_Float16)tile[c4 + 3][hw];
        *(f16x4*)(dst + (size_t)hw * 128 + c4) = o;
    }
}

// ---------------------------------------------------------------------------
// Kernel: weight [O][C][3][3] fp32 -> wt [tap][swizzled O*C] fp16.
// Pre-swizzled so adc_main's staging is a LINEAR copy (global_load_lds-able)
// and the MFMA-phase read keeps the conflict-spread XOR pattern.
// Element (o, c) lands at uint4-index (o<<4)|((c>>3)^(o&7)), half (c&7).
// (v3-proven correct.)
// ---------------------------------------------------------------------------
__global__ void transpose_w_kernel(const float* __restrict__ w, _Float16* __restrict__ wt) {
    int t = blockIdx.x * 256 + threadIdx.x;   // 16384 threads
    int o = t >> 7, c = t & 127;
    int g = c >> 3;
    int dst = (((o << 4) | (g ^ (o & 7))) << 3) | (c & 7);
    const float* s = w + (size_t)(o * 128 + c) * 9;
#pragma unroll
    for (int tap = 0; tap < 9; ++tap)
        wt[tap * 16384 + dst] = (_Float16)s[tap];
}

// ---------------------------------------------------------------------------
// Gather helpers for adc_main. KH/KW passed as ints; fully folded under the
// unrolled tap loop. Each 16-lane group (grp) owns 8 px; lane gl loads the
// 16B channel-chunk gl of each needed corner row (2 segments/instr).
// ---------------------------------------------------------------------------
__device__ __forceinline__ void gather_issue(
    int KH, int KW, U4H (&G)[4][4], int j0, int grp, int gl, unsigned nbase,
    const _Float16* __restrict__ in_cl,
    const int (*sPYi)[PT], const int (*sPXi)[PT])
{
    const unsigned lo = (unsigned)(gl * 8);
#pragma unroll
    for (int jj = 0; jj < 4; ++jj) {
        int px = grp * 8 + j0 + jj;
        int y0 = sPYi[KH][px];
        int x0 = sPXi[KW][px];
        int yc0 = min(y0, H_ - 1), yc1 = min(y0 + 1, H_ - 1);
        int xc0 = min(x0, W_ - 1), xc1 = min(x0 + 1, W_ - 1);
        G[jj][0].u = *(const uint4*)(in_cl + (((nbase + (unsigned)(yc0 * W_ + xc0)) << 7) + lo));
        if (KW != 0)
            G[jj][1].u = *(const uint4*)(in_cl + (((nbase + (unsigned)(yc0 * W_ + xc1)) << 7) + lo));
        if (KH != 0)
            G[jj][2].u = *(const uint4*)(in_cl + (((nbase + (unsigned)(yc1 * W_ + xc0)) << 7) + lo));
        if (KH != 0 && KW != 0)
            G[jj][3].u = *(const uint4*)(in_cl + (((nbase + (unsigned)(yc1 * W_ + xc1)) << 7) + lo));
    }
}

__device__ __forceinline__ void gather_lerp_store(
    int KH, int KW, U4H (&G)[4][4], int j0, int grp, int gl,
    _Float16* sS,
    const int (*sPYi)[PT], const float (*sPYf)[PT],
    const int (*sPXi)[PT], const float (*sPXf)[PT])
{
#pragma unroll
    for (int jj = 0; jj < 4; ++jj) {
        int j  = j0 + jj;                 // 0..7  (== px & 7)
        int px = grp * 8 + j;
        U4H S;
        if (KH == 0 && KW == 0) {
            S = G[jj][0];                 // wy=wx=0 exactly: passthrough
        } else {
            int   y0 = sPYi[KH][px];  float wy = sPYf[KH][px];   // LDS broadcast
            int   x0 = sPXi[KW][px];  float wx = sPXf[KW][px];
            float vy0 = (y0 <= H_ - 1) ? 1.0f : 0.0f;
            float vy1 = (y0 <= H_ - 2) ? 1.0f : 0.0f;
            float vx0 = (x0 <= W_ - 1) ? 1.0f : 0.0f;
            float vx1 = (x0 <= W_ - 2) ? 1.0f : 0.0f;
            __half2 w00 = __float2half2_rn((1.0f - wy) * (1.0f - wx) * vy0 * vx0);
            __half2 w01 = __float2half2_rn((1.0f - wy) * wx * vy0 * vx1);
            __half2 w10 = __float2half2_rn(wy * (1.0f - wx) * vy1 * vx0);
            __half2 w11 = __float2half2_rn(wy * wx * vy1 * vx1);
#pragma unroll
            for (int d = 0; d < 4; ++d) {
                __half2 s = __hmul2(G[jj][0].h[d], w00);
                if (KW != 0)              s = __hfma2(G[jj][1].h[d], w01, s);
                if (KH != 0)              s = __hfma2(G[jj][2].h[d], w10, s);
                if (KH != 0 && KW != 0)   s = __hfma2(G[jj][3].h[d], w11, s);
                S.h[d] = s;
            }
        }
        // XOR chunk-swizzle: phys 16B-chunk = gl ^ (px&7); px&7 == j here.
        *(f16x8*)&sS[px * 128 + ((unsigned)(gl ^ j)) * 8] = S.f;
    }
}

// ---------------------------------------------------------------------------
// Main kernel v4 = R0 baseline structure + T14 async overlap.
// Per tap t:
//   [glds sW(t) issued at loop top — latency hides under lerp/batch1]
//   lerp+store batch0 (issued during tap t-1's MFMA phase)
//   issue+lerp+store batch1 (exposed; covered by sibling block)
//   barrier (drains glds + gathers; sS+sW ready)
//   issue batch0 of tap t+1  -> flies during MFMA
//   MFMA phase (A from sW swizzled, B from sS swizzled)
//   barrier
// LDS = sW 32K + sS 32K (flat, XOR-swizzled) + params 6K = 71.7K -> 2 blk/CU.
// VGPR peak ~ 64 acc + 64 gather-in-flight + temps ~ 180 < 256 (no spill).
// ---------------------------------------------------------------------------
__global__ __launch_bounds__(256, 2) void adc_main(
    const _Float16* __restrict__ in_cl, const _Float16* __restrict__ wt,
    const float* __restrict__ rates, const float* __restrict__ bias,
    float* __restrict__ out)
{
    __shared__ uint4    sW[2048];                       // 32768 B
    __shared__ __align__(16) _Float16 sS[PT * 128];     // 32768 B, swizzled
    __shared__ int      sPYi[3][PT];
    __shared__ float    sPYf[3][PT];
    __shared__ int      sPXi[3][PT];
    __shared__ float    sPXf[3][PT];                    // 6144 B

    const int t    = threadIdx.x;
    const int lane = t & 63;
    const int wv   = t >> 6;
    const int l15  = lane & 15;
    const int quad = lane >> 4;

    const int n     = blockIdx.x & 7;
    const int pbase = (blockIdx.x >> 3) * PT;
    const unsigned nbase = (unsigned)n << 14;

    // ---- once-per-block param precompute (fused rate bilinear) ----
    if (t < PT) {
        int rem = min(pbase + t, PIXPER - 1);
        int ho = rem / WO, wo = rem - ho * WO;
        const float sc = 32.0f / 126.0f;
        float sy = fminf(fmaxf(((float)ho + 0.5f) * sc - 0.5f, 0.0f), 31.0f);
        float sx = fminf(fmaxf(((float)wo + 0.5f) * sc - 0.5f, 0.0f), 31.0f);
        int y0 = (int)sy, x0 = (int)sx;
        int y1 = min(y0 + 1, 31), x1 = min(x0 + 1, 31);
        float wy = sy - (float)y0, wx = sx - (float)x0;
        float r = rates[y0 * 32 + x0] * (1.0f - wy) * (1.0f - wx)
                + rates[y0 * 32 + x1] * (1.0f - wy) * wx
                + rates[y1 * 32 + x0] * wy * (1.0f - wx)
                + rates[y1 * 32 + x1] * wy * wx;
#pragma unroll
        for (int k = 0; k < 3; ++k) {
            float fy  = (float)ho + (float)k * r;   // exact int when k==0
            float fy0 = floorf(fy);
            sPYi[k][t] = (int)fy0;
            sPYf[k][t] = fy - fy0;
            float fx  = (float)wo + (float)k * r;
            float fx0 = floorf(fx);
            sPXi[k][t] = (int)fx0;
            sPXf[k][t] = fx - fx0;
        }
    }

    f32x4 acc[8][2];
    const f32x4 zero = {0.0f, 0.0f, 0.0f, 0.0f};
#pragma unroll
    for (int i = 0; i < 8; ++i) { acc[i][0] = zero; acc[i][1] = zero; }

    const int grp = t >> 4;        // 16 row-groups
    const int gl  = t & 15;        // lane in group: channel chunk gl*8..gl*8+8

    __syncthreads();               // params ready

    U4H G[4][4];                   // 4 px x 4 corners in flight (<=64 VGPR)

    // prologue: issue tap0 batch0
    gather_issue(0, 0, G, 0, grp, gl, nbase, in_cl, sPYi, sPXi);

#pragma unroll
    for (int tap = 0; tap < 9; ++tap) {
        const int kh = tap / 3;            // compile-time after unroll
        const int kw = tap - kh * 3;

        // ---- stage W[tap]: linear async copy, issued early (hides latency
        //      under the lerp/batch1 work below; safe: prev MFMA done) ----
        const uint4* wsrc = (const uint4*)(wt + tap * 16384);
#pragma unroll
        for (int i = 0; i < 8; ++i) {
            int base = i * 256 + (wv << 6);
            GLLDS(wsrc + base + lane, &sW[base]);
        }

        // ---- phase A: batch0 (in flight since prev MFMA), then batch1 ----
        gather_lerp_store(kh, kw, G, 0, grp, gl, sS, sPYi, sPYf, sPXi, sPXf);
        gather_issue(kh, kw, G, 4, grp, gl, nbase, in_cl, sPYi, sPXi);
        gather_lerp_store(kh, kw, G, 4, grp, gl, sS, sPYi, sPYf, sPXi, sPXf);

        __syncthreads();                   // drains glds+gathers; sS+sW ready

        // ---- prefetch next tap's batch0 (flies during MFMA) ----
        if (tap < 8) {
            const int tap1 = tap + 1;
            const int kh1 = tap1 / 3;
            const int kw1 = tap1 - kh1 * 3;
            gather_issue(kh1, kw1, G, 0, grp, gl, nbase, in_cl, sPYi, sPXi);
        }

        // ---- phase B: MFMA, A from sW (XOR swizzle), B from sS (XOR swizzle)
#pragma unroll
        for (int ks = 0; ks < 4; ++ks) {
            const int g  = (ks << 2) | quad;
            const int sw = g ^ (l15 & 7);
            f16x8 b0 = *(const f16x8*)&sS[(wv * 32 +      l15) * 128 + sw * 8];
            f16x8 b1 = *(const f16x8*)&sS[(wv * 32 + 16 + l15) * 128 + sw * 8];
#pragma unroll
            for (int mt = 0; mt < 8; ++mt) {
                int o = (mt << 4) | l15;
                U4H AF;
                AF.u = sW[(o << 4) | sw];  // o&7 == l15&7
                acc[mt][0] = __builtin_amdgcn_mfma_f32_16x16x32_f16(AF.f, b0, acc[mt][0], 0, 0, 0);
                acc[mt][1] = __builtin_amdgcn_mfma_f32_16x16x32_f16(AF.f, b1, acc[mt][1], 0, 0, 0);
            }
        }
        __syncthreads();                   // protect sS/sW overwrite next tap
    }

    // ---- epilogue: R3-proven direct strided stores (unchanged) ----
#pragma unroll
    for (int pt = 0; pt < 2; ++pt) {
        int p    = (wv << 5) + (pt << 4) + l15;
        int prel = pbase + p;
        int rem2 = min(prel, PIXPER - 1);
        float* obase = out + (size_t)n * (COUT * PIXPER) + rem2;
        if (prel < PIXPER) {
#pragma unroll
            for (int mt = 0; mt < 8; ++mt) {
                int o0 = (mt << 4) + (quad << 2);
                float4 bs = *(const float4*)(bias + o0);
                f32x4 a0 = acc[mt][pt];
                obase[(size_t)(o0 + 0) * PIXPER] = a0[0] + bs.x;
                obase[(size_t)(o0 + 1) * PIXPER] = a0[1] + bs.y;
                obase[(size_t)(o0 + 2) * PIXPER] = a0[2] + bs.z;
                obase[(size_t)(o0 + 3) * PIXPER] = a0[3] + bs.w;
            }
        }
    }
}

// ---------------------------------------------------------------------------
extern "C" void kernel_launch(void* const* d_in, const int* in_sizes, int n_in,
                              void* d_out, int out_size, void* d_ws, size_t ws_size,
                              hipStream_t stream) {
    const float* inputs = (const float*)d_in[0];   // [8,128,128,128]
    const float* weight = (const float*)d_in[1];   // [128,128,3,3]
    const float* rates  = (const float*)d_in[2];   // [1,1,32,32]
    const float* bias   = (const float*)d_in[3];   // [128]
    float* out = (float*)d_out;                    // [8,128,126,126]

    char* ws = (char*)d_ws;
    _Float16* in_cl = (_Float16*)ws;                         // 33,554,432 B
    _Float16* wtp   = (_Float16*)(ws + 33554432);            //    294,912 B

    transpose_w_kernel<<<64, 256, 0, stream>>>(weight, wtp);
    transpose_in_kernel<<<4096, 256, 0, stream>>>(inputs, in_cl);
    adc_main<<<NBLK, 256, 0, stream>>>(in_cl, wtp, rates, bias, out);
}